// Round 19
// baseline (792.804 us; speedup 1.0000x reference)
//
#include <hip/hip_runtime.h>
#include <cstdint>

#define DD 128
#define LL 64
#define NCHUNK 256          // edge chunks (radix pass A/C blocks)
#define BPAD 784            // bucket-count row stride (>= NBK=(n+127)>>7, 16-aligned)
#define AGST 68             // agg LDS row stride (padded: groups spread banks)

typedef short short8 __attribute__((ext_vector_type(8)));
typedef float f32x4 __attribute__((ext_vector_type(4)));

static __device__ __forceinline__ unsigned short f2bf(float f) {
    unsigned u = __float_as_uint(f);
    unsigned r = (u + 0x7FFFu + ((u >> 16) & 1u)) >> 16;   // round-to-nearest-even
    return (unsigned short)r;
}
static __device__ __forceinline__ float bflo(unsigned u) {   // low bf16 of packed pair
    return __uint_as_float(u << 16);
}
static __device__ __forceinline__ float bfhi(unsigned u) {   // high bf16 of packed pair
    return __uint_as_float(u & 0xFFFF0000u);
}
static __device__ __forceinline__ uint4 pack8(float4 lo, float4 hi) {
    uint4 u;
    u.x = (unsigned)f2bf(lo.x) | ((unsigned)f2bf(lo.y) << 16);
    u.y = (unsigned)f2bf(lo.z) | ((unsigned)f2bf(lo.w) << 16);
    u.z = (unsigned)f2bf(hi.x) | ((unsigned)f2bf(hi.y) << 16);
    u.w = (unsigned)f2bf(hi.z) | ((unsigned)f2bf(hi.w) << 16);
    return u;
}

// ---------------- prologue: W1_rel||W1_root -> combined bf16 wb[128][128] ----------------
__global__ __launch_bounds__(256) void kW(const float* __restrict__ Wrel, const float* __restrict__ Wroot,
        unsigned short* __restrict__ wb)
{
    int c = blockIdx.x * 256 + threadIdx.x;   // 2048 chunks of 8 elements
    if (c >= 2048) return;
    int r = c >> 4, cb = (c & 15) * 8;
    const float* srcp = (r < 64) ? (Wrel + (size_t)r * DD + cb) : (Wroot + (size_t)(r - 64) * DD + cb);
    float4 lo = *(const float4*)srcp;
    float4 hi = *(const float4*)(srcp + 4);
    *(uint4*)(wb + (size_t)r * DD + cb) = pack8(lo, hi);
}

// ---------------- fused: radix pass A (chunk histograms, blocks [0,NCHUNK)) + MFMA GEMM ----------------
__global__ __launch_bounds__(256) void k1_scat(const float* __restrict__ x,
        const unsigned short* __restrict__ wb,
        const int* __restrict__ dst, int* __restrict__ cm,
        unsigned short* __restrict__ yb, unsigned short* __restrict__ zb,
        int n, int E)
{
    __shared__ __align__(16) unsigned short xa[64 * 128];    // 16KB; hist alias / GEMM stage / epilogue
    int tid = threadIdx.x;
    if (blockIdx.x < NCHUNK) {                  // ---- pass A: chunk histogram ----
        int* hist = (int*)xa;
        int c = blockIdx.x;
        for (int i = tid; i < BPAD; i += 256) hist[i] = 0;
        __syncthreads();
        int CH = (E + NCHUNK - 1) / NCHUNK;
        int base = c * CH, end = base + CH; if (end > E) end = E;
        for (int e = base + tid; e < end; e += 256)
            atomicAdd(&hist[dst[e] >> 7], 1);                 // LDS atomic
        __syncthreads();
        for (int i = tid; i < BPAD; i += 256) cm[c * BPAD + i] = hist[i];
        return;
    }
    // ---- GEMM part: [yb|zb] = bf16(x @ [W1_rel|W1_root]^T) ----
    int nbase = (blockIdx.x - NCHUNK) * 64;

    { // stage x: 4 lanes per row (coalesced: each wave reads 16 rows contiguous)
        int r = tid >> 2, cb = (tid & 3) * 4;
        int node = nbase + r; if (node >= n) node = n - 1;
        const float4* xp = (const float4*)(x + (size_t)node * DD);
        #pragma unroll
        for (int c = 0; c < 4; ++c) {
            float4 lo = xp[(cb + c) * 2], hi = xp[(cb + c) * 2 + 1];
            int slot = (cb + c + r) & 15;
            *(uint4*)&xa[r * 128 + slot * 8] = pack8(lo, hi);
        }
    }
    __syncthreads();

    int lane = tid & 63;
    int w = __builtin_amdgcn_readfirstlane(tid >> 6);
    int lr = lane & 15, lk = lane >> 4;
    int wrowbase = w * 32;

    f32x4 acc[4][2];
    #pragma unroll
    for (int tr = 0; tr < 4; ++tr)
        #pragma unroll
        for (int tc = 0; tc < 2; ++tc)
            acc[tr][tc] = (f32x4){0.f, 0.f, 0.f, 0.f};

    #pragma unroll
    for (int kk = 0; kk < 4; ++kk) {
        int c = kk * 4 + lk;
        short8 bfrag[2];
        #pragma unroll
        for (int tc = 0; tc < 2; ++tc)        // single 16B load from L2-hot preconverted wb
            bfrag[tc] = *(const short8*)(wb + (size_t)(wrowbase + tc * 16 + lr) * DD + kk * 32 + lk * 8);
        #pragma unroll
        for (int tr = 0; tr < 4; ++tr) {
            int arow = tr * 16 + lr;
            short8 afrag = *(const short8*)&xa[arow * 128 + ((c + arow) & 15) * 8];
            acc[tr][0] = __builtin_amdgcn_mfma_f32_16x16x32_bf16(afrag, bfrag[0], acc[tr][0], 0, 0, 0);
            acc[tr][1] = __builtin_amdgcn_mfma_f32_16x16x32_bf16(afrag, bfrag[1], acc[tr][1], 0, 0, 0);
        }
    }

    __syncthreads();                 // xa reads done; reuse as epilogue buffer
    unsigned short* ob = xa;         // [64 rows][128 cols] bf16, 32B-group XOR swizzle
    #pragma unroll
    for (int tr = 0; tr < 4; ++tr) {
        #pragma unroll
        for (int tc = 0; tc < 2; ++tc) {
            int col = w * 32 + tc * 16 + lr;      // C/D: col=lane&15 [m89]
            int cg = col >> 4, ci = col & 15;
            #pragma unroll
            for (int r = 0; r < 4; ++r) {
                int row = tr * 16 + lk * 4 + r;   // C/D: row=(lane>>4)*4+reg [m89]
                ob[row * 128 + ((cg ^ (row & 7)) << 4) + ci] = f2bf(acc[tr][tc][r]);
            }
        }
    }
    __syncthreads();

    { // coalesced store: yb = cols 0-63, zb = cols 64-127
        int row = tid >> 2, part = tid & 3;
        int node = nbase + row;
        if (node < n) {
            int by = row * 128 + ((part ^ (row & 7)) << 4);
            uint4 a0 = *(uint4*)&ob[by];
            uint4 a1 = *(uint4*)&ob[by + 8];
            *(uint4*)(yb + (size_t)node * LL + part * 16) = a0;
            *(uint4*)(yb + (size_t)node * LL + part * 16 + 8) = a1;
            int bz = row * 128 + (((part + 4) ^ (row & 7)) << 4);
            uint4 b0 = *(uint4*)&ob[bz];
            uint4 b1 = *(uint4*)&ob[bz + 8];
            *(uint4*)(zb + (size_t)node * LL + part * 16) = b0;
            *(uint4*)(zb + (size_t)node * LL + part * 16 + 8) = b1;
        }
    }
}

// ---------------- radix pass B1: per-bucket column rewrite (parallel) ----------------
__global__ __launch_bounds__(256) void kB1(int* __restrict__ cm, int* __restrict__ btot) {
    int b = blockIdx.x * 256 + threadIdx.x;
    if (b >= BPAD) return;
    int run = 0;
    for (int c = 0; c < NCHUNK; ++c) {
        int v = cm[c * BPAD + b];
        cm[c * BPAD + b] = run;
        run += v;
    }
    btot[b] = run;
}

// ---------------- radix pass B2: scan bucket totals -> bbase ----------------
__global__ __launch_bounds__(1024) void kB2(const int* __restrict__ btot, int* __restrict__ bbase) {
    __shared__ int sc[1024];
    int b = threadIdx.x;
    int v = (b < BPAD) ? btot[b] : 0;
    sc[b] = v;
    __syncthreads();
    for (int off = 1; off < 1024; off <<= 1) {
        int add = (b >= off) ? sc[b - off] : 0;
        __syncthreads();
        sc[b] += add;
        __syncthreads();
    }
    if (b < BPAD) bbase[b] = sc[b] - v;
    if (b == 1023) bbase[BPAD] = sc[b];      // = E
}

// ---------------- radix pass C: place edges into bucket-sorted order ----------------
__global__ __launch_bounds__(256) void kC(const int* __restrict__ src, const int* __restrict__ dst,
        const int* __restrict__ cm, const int* __restrict__ bbase, int* __restrict__ sorted, int E)
{
    __shared__ int run[BPAD];
    int c = blockIdx.x;
    for (int i = threadIdx.x; i < BPAD; i += 256) run[i] = cm[c * BPAD + i] + bbase[i];
    __syncthreads();
    int CH = (E + NCHUNK - 1) / NCHUNK;
    int base = c * CH, end = base + CH; if (end > E) end = E;
    for (int e = base + threadIdx.x; e < end; e += 256) {
        int d = dst[e];
        int pos = atomicAdd(&run[d >> 7], 1);             // LDS atomic; positions exact
        sorted[pos] = ((d & 127) << 17) | src[e];         // src < 2^17 (n <= 131071)
    }
}

// ---------------- fused layer-1 aggregate (per bucket, LDS f32) + h + s,t ----------------
// Round-18 restructure: consumes bucket-contiguous sorted[] directly — kD and
// the whole csr_pad round-trip (25.6MB w + ~19MB r) deleted. 16-lane groups
// gather y rows (2-deep unroll -> 8 edges in flight/wave); LDS atomicAdd f32
// into agg[128][AGST=68] (padded stride: concurrent groups spread banks).
__global__ __launch_bounds__(512) void k3b(const unsigned short* __restrict__ yb, const unsigned short* __restrict__ zb,
        const int* __restrict__ sorted, const int* __restrict__ bbase,
        const float* __restrict__ b1, const float* __restrict__ w2rel, const float* __restrict__ w2root,
        float* __restrict__ s, float* __restrict__ t, int n)
{
    __shared__ float agg[128 * AGST];   // 34.8KB
    int tid = threadIdx.x;
    int b = blockIdx.x;
    int lo = bbase[b], hi = bbase[b + 1];
    for (int i = tid; i < 128 * AGST; i += 512) agg[i] = 0.f;
    __syncthreads();

    int c4 = tid & 15, gq = tid >> 4;     // 32 groups of 16 lanes
    for (int e = lo + gq; e < hi; e += 64) {
        int v0 = sorted[e];
        int e1 = e + 32;
        bool p1 = e1 < hi;
        int v1 = p1 ? sorted[e1] : v0;
        uint2 u0 = *(const uint2*)(yb + (size_t)(v0 & 0x1FFFF) * LL + c4 * 4);
        uint2 u1 = *(const uint2*)(yb + (size_t)(v1 & 0x1FFFF) * LL + c4 * 4);
        float* a0 = &agg[(v0 >> 17) * AGST + c4 * 4];
        atomicAdd(&a0[0], bflo(u0.x));
        atomicAdd(&a0[1], bfhi(u0.x));
        atomicAdd(&a0[2], bflo(u0.y));
        atomicAdd(&a0[3], bfhi(u0.y));
        if (p1) {
            float* a1 = &agg[(v1 >> 17) * AGST + c4 * 4];
            atomicAdd(&a1[0], bflo(u1.x));
            atomicAdd(&a1[1], bfhi(u1.x));
            atomicAdd(&a1[2], bflo(u1.y));
            atomicAdd(&a1[3], bfhi(u1.y));
        }
    }
    __syncthreads();

    // epilogue: 4 threads per node, 16 features each
    int node_l = tid >> 2, fb = (tid & 3) * 16;
    int node = b * 128 + node_l;
    if (node < n) {
        float sv = 0.f, tv = 0.f;
        const float* ap = &agg[node_l * AGST + fb];
        const unsigned short* zp = zb + (size_t)node * LL + fb;
        #pragma unroll
        for (int j = 0; j < 16; j += 4) {
            uint2 uz = *(const uint2*)(zp + j);
            float4 bv = *(const float4*)(b1 + fb + j);
            float4 wr = *(const float4*)(w2rel + fb + j);
            float4 wo = *(const float4*)(w2root + fb + j);
            float h0 = ap[j + 0] + bflo(uz.x) + bv.x;
            float h1 = ap[j + 1] + bfhi(uz.x) + bv.y;
            float h2 = ap[j + 2] + bflo(uz.y) + bv.z;
            float h3 = ap[j + 3] + bfhi(uz.y) + bv.w;
            h0 = h0 > 0.f ? h0 : 0.2f * h0;      // leaky_relu(0.2)
            h1 = h1 > 0.f ? h1 : 0.2f * h1;
            h2 = h2 > 0.f ? h2 : 0.2f * h2;
            h3 = h3 > 0.f ? h3 : 0.2f * h3;
            sv += h0 * wr.x + h1 * wr.y + h2 * wr.z + h3 * wr.w;
            tv += h0 * wo.x + h1 * wo.y + h2 * wo.z + h3 * wo.w;
        }
        sv += __shfl_xor(sv, 1, 64); sv += __shfl_xor(sv, 2, 64);
        tv += __shfl_xor(tv, 1, 64); tv += __shfl_xor(tv, 2, 64);
        if ((tid & 3) == 0) { s[node] = sv; t[node] = tv; }
    }
}

// ---------------- fused gate logits (per bucket) + per-bucket online-softmax (m,Z) ----------------
static __device__ __forceinline__ void smcomb(float& m, float& Z, float m2, float Z2) {
    float M = fmaxf(m, m2);
    Z = Z * expf(m - M) + Z2 * expf(m2 - M);
    m = M;
}

__global__ __launch_bounds__(256) void k5b(const float* __restrict__ s, const float* __restrict__ t,
        const int* __restrict__ sorted, const int* __restrict__ bbase, const float* __restrict__ b2,
        float* __restrict__ g, float2* __restrict__ pairs, int n)
{
    __shared__ float gate[128];
    __shared__ float sm[256], sz[256];
    int tid = threadIdx.x;
    int b = blockIdx.x;
    int lo = bbase[b], hi = bbase[b + 1];
    if (tid < 128) gate[tid] = 0.f;
    __syncthreads();
    for (int e = lo + tid; e < hi; e += 256) {
        int v = sorted[e];
        atomicAdd(&gate[v >> 17], s[v & 0x1FFFF]);   // s table 400KB, L2-hot
    }
    __syncthreads();
    float m = -3.402823466e38f, Z = 0.f;
    int node = b * 128 + tid;
    if (tid < 128 && node < n) {
        float acc = gate[tid] + b2[0] + t[node];
        g[node] = acc;
        m = acc; Z = 1.f;
    }
    sm[tid] = m; sz[tid] = Z;
    __syncthreads();
    for (int off = 128; off > 0; off >>= 1) {
        if (tid < off) {
            float mm = sm[tid], ZZ = sz[tid];
            smcomb(mm, ZZ, sm[tid + off], sz[tid + off]);
            sm[tid] = mm; sz[tid] = ZZ;
        }
        __syncthreads();
    }
    if (tid == 0) pairs[b] = make_float2(sm[0], sz[0]);
}

__global__ __launch_bounds__(256) void k6b(const float2* __restrict__ pairs, float* __restrict__ scalars, int nb) {
    __shared__ float sm[256], sz[256];
    float m = -3.402823466e38f, Z = 0.f;
    for (int j = threadIdx.x; j < nb; j += 256) {
        float2 p = pairs[j];
        smcomb(m, Z, p.x, p.y);
    }
    sm[threadIdx.x] = m; sz[threadIdx.x] = Z;
    __syncthreads();
    for (int off = 128; off > 0; off >>= 1) {
        if (threadIdx.x < off) {
            float mm = sm[threadIdx.x], ZZ = sz[threadIdx.x];
            smcomb(mm, ZZ, sm[threadIdx.x + off], sz[threadIdx.x + off]);
            sm[threadIdx.x] = mm; sz[threadIdx.x] = ZZ;
        }
        __syncthreads();
    }
    if (threadIdx.x == 0) { scalars[0] = sm[0]; scalars[1] = sz[0]; }
}

// ---------------- out[d] = sum_i softmax(g)_i * x[i,d] ----------------
__global__ __launch_bounds__(256) void k6_out(const float* __restrict__ x, const float* __restrict__ g,
        const float* __restrict__ scalars, float* __restrict__ out, int n)
{
    __shared__ float acc_s[4][DD];
    int wave = threadIdx.x >> 6, lane = threadIdx.x & 63;
    float m = scalars[0];
    float invZ = 1.0f / scalars[1];
    float a0 = 0.f, a1 = 0.f;
    int gw = blockIdx.x * 4 + wave;
    int nw = gridDim.x * 4;
    for (int i = gw; i < n; i += nw) {
        float w = expf(g[i] - m) * invZ;
        a0 += w * x[(size_t)i * DD + lane];
        a1 += w * x[(size_t)i * DD + 64 + lane];
    }
    acc_s[wave][lane] = a0;
    acc_s[wave][lane + 64] = a1;
    __syncthreads();
    if (wave == 0) {
        float v0 = acc_s[0][lane] + acc_s[1][lane] + acc_s[2][lane] + acc_s[3][lane];
        float v1 = acc_s[0][lane + 64] + acc_s[1][lane + 64] + acc_s[2][lane + 64] + acc_s[3][lane + 64];
        atomicAdd(&out[lane], v0);
        atomicAdd(&out[lane + 64], v1);
    }
}

extern "C" void kernel_launch(void* const* d_in, const int* in_sizes, int n_in,
                              void* d_out, int out_size, void* d_ws, size_t ws_size,
                              hipStream_t stream)
{
    const float* x      = (const float*)d_in[0];
    const int*   eidx   = (const int*)d_in[1];
    const float* W1rel  = (const float*)d_in[2];
    const float* b1     = (const float*)d_in[3];
    const float* W1root = (const float*)d_in[4];
    const float* W2rel  = (const float*)d_in[5];
    const float* b2     = (const float*)d_in[6];
    const float* W2root = (const float*)d_in[7];
    float* out = (float*)d_out;

    int n = in_sizes[0] / DD;
    int E = in_sizes[1] / 2;
    const int* src = eidx;
    const int* dstp = eidx + E;
    int NBK = (n + 127) >> 7;                 // buckets (<= BPAD)

    char* ws = (char*)d_ws;
    size_t off = 0;
    auto alloc = [&](size_t bytes) -> char* {
        char* p = ws + off;
        off = (off + bytes + 255) & ~(size_t)255;
        return p;
    };
    unsigned short* yb = (unsigned short*)alloc((size_t)n * LL * 2);
    unsigned short* zb = (unsigned short*)alloc((size_t)n * LL * 2);
    unsigned short* wb = (unsigned short*)alloc((size_t)DD * DD * 2);
    int*   cm      = (int*)  alloc((size_t)NCHUNK * BPAD * 4);
    int*   btot    = (int*)  alloc((size_t)BPAD * 4);
    int*   bbase   = (int*)  alloc((size_t)(BPAD + 1) * 4);
    int*   sorted  = (int*)  alloc((size_t)E * 4);
    float* s       = (float*)alloc((size_t)n * 4);
    float* t       = (float*)alloc((size_t)n * 4);
    float* g       = (float*)alloc((size_t)n * 4);
    float2* pairs  = (float2*)alloc((size_t)NBK * 8);
    float* scalars = (float*)alloc(2 * 4);
    (void)ws_size; (void)n_in;

    hipMemsetAsync(d_out, 0, (size_t)out_size * 4, stream);

    int nblk1 = (n + 63) / 64;
    kW<<<8, 256, 0, stream>>>(W1rel, W1root, wb);
    k1_scat<<<NCHUNK + nblk1, 256, 0, stream>>>(x, wb, dstp, cm, yb, zb, n, E);
    kB1<<<(BPAD + 255) / 256, 256, 0, stream>>>(cm, btot);
    kB2<<<1, 1024, 0, stream>>>(btot, bbase);
    kC<<<NCHUNK, 256, 0, stream>>>(src, dstp, cm, bbase, sorted, E);
    k3b<<<NBK, 512, 0, stream>>>(yb, zb, sorted, bbase, b1, W2rel, W2root, s, t, n);
    k5b<<<NBK, 256, 0, stream>>>(s, t, sorted, bbase, b2, g, pairs, n);
    k6b<<<1, 256, 0, stream>>>(pairs, scalars, NBK);
    k6_out<<<512, 256, 0, stream>>>(x, g, scalars, out, n);
}

// Round 20
// 178.397 us; speedup vs baseline: 4.4441x; 4.4441x over previous
//
#include <hip/hip_runtime.h>
#include <cstdint>

#define DD 128
#define LL 64
#define PSTRIDE 64          // padded CSR slots per node (Poisson(16), max deg ~45)
#define NCHUNK 256          // edge chunks (radix pass A/C blocks)
#define BPAD 784            // bucket-count row stride (>= NB=(n+127)>>7, 16-aligned)

typedef short short8 __attribute__((ext_vector_type(8)));
typedef float f32x4 __attribute__((ext_vector_type(4)));

static __device__ __forceinline__ unsigned short f2bf(float f) {
    unsigned u = __float_as_uint(f);
    unsigned r = (u + 0x7FFFu + ((u >> 16) & 1u)) >> 16;   // round-to-nearest-even
    return (unsigned short)r;
}
static __device__ __forceinline__ float bflo(unsigned u) {   // low bf16 of packed pair
    return __uint_as_float(u << 16);
}
static __device__ __forceinline__ float bfhi(unsigned u) {   // high bf16 of packed pair
    return __uint_as_float(u & 0xFFFF0000u);
}
static __device__ __forceinline__ uint4 pack8(float4 lo, float4 hi) {
    uint4 u;
    u.x = (unsigned)f2bf(lo.x) | ((unsigned)f2bf(lo.y) << 16);
    u.y = (unsigned)f2bf(lo.z) | ((unsigned)f2bf(lo.w) << 16);
    u.z = (unsigned)f2bf(hi.x) | ((unsigned)f2bf(hi.y) << 16);
    u.w = (unsigned)f2bf(hi.z) | ((unsigned)f2bf(hi.w) << 16);
    return u;
}

// ---------------- prologue: W1_rel||W1_root -> combined bf16 wb[128][128] ----------------
// Round-19 lesson (recorded): f32 atomicAdd on LDS compiles to a CAS retry
// loop (VALUBusy 1.5%, 677us) — only INT LDS atomics are cheap. The fused
// per-bucket k3b was reverted; this file is the measured-best round-18 config.
__global__ __launch_bounds__(256) void kW(const float* __restrict__ Wrel, const float* __restrict__ Wroot,
        unsigned short* __restrict__ wb)
{
    int c = blockIdx.x * 256 + threadIdx.x;   // 2048 chunks of 8 elements
    if (c >= 2048) return;
    int r = c >> 4, cb = (c & 15) * 8;
    const float* srcp = (r < 64) ? (Wrel + (size_t)r * DD + cb) : (Wroot + (size_t)(r - 64) * DD + cb);
    float4 lo = *(const float4*)srcp;
    float4 hi = *(const float4*)(srcp + 4);
    *(uint4*)(wb + (size_t)r * DD + cb) = pack8(lo, hi);
}

// ---------------- fused: radix pass A (chunk histograms, blocks [0,NCHUNK)) + MFMA GEMM ----------------
__global__ __launch_bounds__(256) void k1_scat(const float* __restrict__ x,
        const unsigned short* __restrict__ wb,
        const int* __restrict__ dst, int* __restrict__ cm,
        unsigned short* __restrict__ yb, unsigned short* __restrict__ zb,
        int n, int E)
{
    __shared__ __align__(16) unsigned short xa[64 * 128];    // 16KB; hist alias / GEMM stage / epilogue
    int tid = threadIdx.x;
    if (blockIdx.x < NCHUNK) {                  // ---- pass A: chunk histogram ----
        int* hist = (int*)xa;
        int c = blockIdx.x;
        for (int i = tid; i < BPAD; i += 256) hist[i] = 0;
        __syncthreads();
        int CH = (E + NCHUNK - 1) / NCHUNK;
        int base = c * CH, end = base + CH; if (end > E) end = E;
        for (int e = base + tid; e < end; e += 256)
            atomicAdd(&hist[dst[e] >> 7], 1);                 // LDS atomic (int: native)
        __syncthreads();
        for (int i = tid; i < BPAD; i += 256) cm[c * BPAD + i] = hist[i];
        return;
    }
    // ---- GEMM part: [yb|zb] = bf16(x @ [W1_rel|W1_root]^T) ----
    int nbase = (blockIdx.x - NCHUNK) * 64;

    { // stage x: 4 lanes per row (coalesced: each wave reads 16 rows contiguous)
        int r = tid >> 2, cb = (tid & 3) * 4;
        int node = nbase + r; if (node >= n) node = n - 1;
        const float4* xp = (const float4*)(x + (size_t)node * DD);
        #pragma unroll
        for (int c = 0; c < 4; ++c) {
            float4 lo = xp[(cb + c) * 2], hi = xp[(cb + c) * 2 + 1];
            int slot = (cb + c + r) & 15;
            *(uint4*)&xa[r * 128 + slot * 8] = pack8(lo, hi);
        }
    }
    __syncthreads();

    int lane = tid & 63;
    int w = __builtin_amdgcn_readfirstlane(tid >> 6);
    int lr = lane & 15, lk = lane >> 4;
    int wrowbase = w * 32;                    // combined wb row block (w*32 + tc*16 + lr)

    f32x4 acc[4][2];
    #pragma unroll
    for (int tr = 0; tr < 4; ++tr)
        #pragma unroll
        for (int tc = 0; tc < 2; ++tc)
            acc[tr][tc] = (f32x4){0.f, 0.f, 0.f, 0.f};

    #pragma unroll
    for (int kk = 0; kk < 4; ++kk) {
        int c = kk * 4 + lk;
        short8 bfrag[2];
        #pragma unroll
        for (int tc = 0; tc < 2; ++tc)        // single 16B load from L2-hot preconverted wb
            bfrag[tc] = *(const short8*)(wb + (size_t)(wrowbase + tc * 16 + lr) * DD + kk * 32 + lk * 8);
        #pragma unroll
        for (int tr = 0; tr < 4; ++tr) {
            int arow = tr * 16 + lr;
            short8 afrag = *(const short8*)&xa[arow * 128 + ((c + arow) & 15) * 8];
            acc[tr][0] = __builtin_amdgcn_mfma_f32_16x16x32_bf16(afrag, bfrag[0], acc[tr][0], 0, 0, 0);
            acc[tr][1] = __builtin_amdgcn_mfma_f32_16x16x32_bf16(afrag, bfrag[1], acc[tr][1], 0, 0, 0);
        }
    }

    __syncthreads();                 // xa reads done; reuse as epilogue buffer
    unsigned short* ob = xa;         // [64 rows][128 cols] bf16, 32B-group XOR swizzle
    #pragma unroll
    for (int tr = 0; tr < 4; ++tr) {
        #pragma unroll
        for (int tc = 0; tc < 2; ++tc) {
            int col = w * 32 + tc * 16 + lr;      // C/D: col=lane&15 [m89]
            int cg = col >> 4, ci = col & 15;
            #pragma unroll
            for (int r = 0; r < 4; ++r) {
                int row = tr * 16 + lk * 4 + r;   // C/D: row=(lane>>4)*4+reg [m89]
                ob[row * 128 + ((cg ^ (row & 7)) << 4) + ci] = f2bf(acc[tr][tc][r]);
            }
        }
    }
    __syncthreads();

    { // coalesced store: yb = cols 0-63, zb = cols 64-127
        int row = tid >> 2, part = tid & 3;
        int node = nbase + row;
        if (node < n) {
            int by = row * 128 + ((part ^ (row & 7)) << 4);
            uint4 a0 = *(uint4*)&ob[by];
            uint4 a1 = *(uint4*)&ob[by + 8];
            *(uint4*)(yb + (size_t)node * LL + part * 16) = a0;
            *(uint4*)(yb + (size_t)node * LL + part * 16 + 8) = a1;
            int bz = row * 128 + (((part + 4) ^ (row & 7)) << 4);
            uint4 b0 = *(uint4*)&ob[bz];
            uint4 b1 = *(uint4*)&ob[bz + 8];
            *(uint4*)(zb + (size_t)node * LL + part * 16) = b0;
            *(uint4*)(zb + (size_t)node * LL + part * 16 + 8) = b1;
        }
    }
}

// ---------------- radix pass B1: per-bucket column rewrite (parallel) ----------------
__global__ __launch_bounds__(256) void kB1(int* __restrict__ cm, int* __restrict__ btot) {
    int b = blockIdx.x * 256 + threadIdx.x;
    if (b >= BPAD) return;
    int run = 0;
    for (int c = 0; c < NCHUNK; ++c) {
        int v = cm[c * BPAD + b];
        cm[c * BPAD + b] = run;
        run += v;
    }
    btot[b] = run;
}

// ---------------- radix pass B2: scan bucket totals -> bbase ----------------
__global__ __launch_bounds__(1024) void kB2(const int* __restrict__ btot, int* __restrict__ bbase) {
    __shared__ int sc[1024];
    int b = threadIdx.x;
    int v = (b < BPAD) ? btot[b] : 0;
    sc[b] = v;
    __syncthreads();
    for (int off = 1; off < 1024; off <<= 1) {
        int add = (b >= off) ? sc[b - off] : 0;
        __syncthreads();
        sc[b] += add;
        __syncthreads();
    }
    if (b < BPAD) bbase[b] = sc[b] - v;
    if (b == 1023) bbase[BPAD] = sc[b];      // = E
}

// ---------------- radix pass C: place edges into bucket-sorted order ----------------
__global__ __launch_bounds__(256) void kC(const int* __restrict__ src, const int* __restrict__ dst,
        const int* __restrict__ cm, const int* __restrict__ bbase, int* __restrict__ sorted, int E)
{
    __shared__ int run[BPAD];
    int c = blockIdx.x;
    for (int i = threadIdx.x; i < BPAD; i += 256) run[i] = cm[c * BPAD + i] + bbase[i];
    __syncthreads();
    int CH = (E + NCHUNK - 1) / NCHUNK;
    int base = c * CH, end = base + CH; if (end > E) end = E;
    for (int e = base + threadIdx.x; e < end; e += 256) {
        int d = dst[e];
        int pos = atomicAdd(&run[d >> 7], 1);             // LDS atomic; positions exact
        sorted[pos] = ((d & 127) << 17) | src[e];         // src < 2^17 (n <= 131071)
    }
}

// ---------------- radix pass D: bucket -> node-padded CSR (plain stores) ----------------
__global__ __launch_bounds__(256) void kD(const int* __restrict__ sorted, const int* __restrict__ bbase,
        int* __restrict__ cnt, int* __restrict__ csr_pad, int n)
{
    __shared__ int hist[128];
    int b = blockIdx.x;
    int lo = bbase[b], hi = bbase[b + 1];
    for (int i = threadIdx.x; i < 128; i += 256) hist[i] = 0;
    __syncthreads();
    for (int e = lo + threadIdx.x; e < hi; e += 256) {
        int v = sorted[e];
        int loc = v >> 17;
        int pos = atomicAdd(&hist[loc], 1);               // LDS atomic = within-node slot
        if (pos < PSTRIDE)
            csr_pad[(size_t)(b * 128 + loc) * PSTRIDE + pos] = v & 0x1FFFF;
    }
    __syncthreads();
    for (int i = threadIdx.x; i < 128; i += 256) {
        int node = b * 128 + i;
        if (node < n) cnt[node] = hist[i];
    }
}

// ---------------- layer-1 aggregate + h + s,t (one wave per node, quarter-lane) ----------------
__global__ __launch_bounds__(256) void k3_agg(const unsigned short* __restrict__ yb, const unsigned short* __restrict__ zb,
        const int* __restrict__ cnt, const int* __restrict__ csr_pad,
        const float* __restrict__ b1, const float* __restrict__ w2rel, const float* __restrict__ w2root,
        float* __restrict__ s, float* __restrict__ t, int n)
{
    int wave = threadIdx.x >> 6, lane = threadIdx.x & 63;
    int i = blockIdx.x * 4 + wave;
    if (i >= n) return;
    int deg = cnt[i]; if (deg > PSTRIDE) deg = PSTRIDE;
    const int* cp = csr_pad + (size_t)i * PSTRIDE;   // wave-uniform -> s_load
    int c4 = lane & 15, q = lane >> 4;               // feature chunk (4 bf16), quarter
    float a0 = 0.f, a1 = 0.f, a2 = 0.f, a3 = 0.f;
    for (int k = 0; k < deg; k += 16) {
        int e0 = k + q, e1 = k + 4 + q, e2 = k + 8 + q, e3 = k + 12 + q;
        uint2 u0 = make_uint2(0u, 0u), u1 = u0, u2 = u0, u3 = u0;
        if (e0 < deg) u0 = *(const uint2*)(yb + (size_t)cp[e0] * LL + c4 * 4);
        if (e1 < deg) u1 = *(const uint2*)(yb + (size_t)cp[e1] * LL + c4 * 4);
        if (e2 < deg) u2 = *(const uint2*)(yb + (size_t)cp[e2] * LL + c4 * 4);
        if (e3 < deg) u3 = *(const uint2*)(yb + (size_t)cp[e3] * LL + c4 * 4);
        a0 += (bflo(u0.x) + bflo(u1.x)) + (bflo(u2.x) + bflo(u3.x));
        a1 += (bfhi(u0.x) + bfhi(u1.x)) + (bfhi(u2.x) + bfhi(u3.x));
        a2 += (bflo(u0.y) + bflo(u1.y)) + (bflo(u2.y) + bflo(u3.y));
        a3 += (bfhi(u0.y) + bfhi(u1.y)) + (bfhi(u2.y) + bfhi(u3.y));
    }
    // collapse quarters (lanes with same c4 hold partial sums)
    a0 += __shfl_xor(a0, 16, 64); a0 += __shfl_xor(a0, 32, 64);
    a1 += __shfl_xor(a1, 16, 64); a1 += __shfl_xor(a1, 32, 64);
    a2 += __shfl_xor(a2, 16, 64); a2 += __shfl_xor(a2, 32, 64);
    a3 += __shfl_xor(a3, 16, 64); a3 += __shfl_xor(a3, 32, 64);

    uint2 uz = *(const uint2*)(zb + (size_t)i * LL + c4 * 4);
    float4 bv = *(const float4*)(b1 + c4 * 4);
    float h0 = a0 + bflo(uz.x) + bv.x;
    float h1 = a1 + bfhi(uz.x) + bv.y;
    float h2 = a2 + bflo(uz.y) + bv.z;
    float h3 = a3 + bfhi(uz.y) + bv.w;
    h0 = h0 > 0.f ? h0 : 0.2f * h0;          // leaky_relu(0.2)
    h1 = h1 > 0.f ? h1 : 0.2f * h1;
    h2 = h2 > 0.f ? h2 : 0.2f * h2;
    h3 = h3 > 0.f ? h3 : 0.2f * h3;
    float4 wr = *(const float4*)(w2rel + c4 * 4);
    float4 wo = *(const float4*)(w2root + c4 * 4);
    float sv = h0 * wr.x + h1 * wr.y + h2 * wr.z + h3 * wr.w;
    float tv = h0 * wo.x + h1 * wo.y + h2 * wo.z + h3 * wo.w;
    #pragma unroll
    for (int o = 8; o >= 1; o >>= 1) {       // reduce across the 16 c4 groups
        sv += __shfl_xor(sv, o, 64);
        tv += __shfl_xor(tv, o, 64);
    }
    if (lane == 0) { s[i] = sv; t[i] = tv; }
}

// ---------------- gate logits + per-block online-softmax (m,Z) ----------------
static __device__ __forceinline__ void smcomb(float& m, float& Z, float m2, float Z2) {
    float M = fmaxf(m, m2);
    Z = Z * expf(m - M) + Z2 * expf(m2 - M);
    m = M;
}

__global__ __launch_bounds__(256) void k5_gate(const float* __restrict__ s, const float* __restrict__ t,
        const int* __restrict__ cnt, const int* __restrict__ csr_pad, const float* __restrict__ b2,
        float* __restrict__ g, float2* __restrict__ pairs, int n)
{
    __shared__ float sm[256], sz[256];
    int i = blockIdx.x * 256 + threadIdx.x;
    float m = -3.402823466e38f, Z = 0.f;
    if (i < n) {
        float acc = b2[0] + t[i];
        int deg = cnt[i]; if (deg > PSTRIDE) deg = PSTRIDE;
        const int* cp = csr_pad + (size_t)i * PSTRIDE;
        int e = 0;
        for (; e + 4 <= deg; e += 4)
            acc += (s[cp[e]] + s[cp[e + 1]]) + (s[cp[e + 2]] + s[cp[e + 3]]);
        for (; e < deg; ++e) acc += s[cp[e]];
        g[i] = acc;
        m = acc; Z = 1.f;
    }
    sm[threadIdx.x] = m; sz[threadIdx.x] = Z;
    __syncthreads();
    for (int off = 128; off > 0; off >>= 1) {
        if (threadIdx.x < off) {
            float mm = sm[threadIdx.x], ZZ = sz[threadIdx.x];
            smcomb(mm, ZZ, sm[threadIdx.x + off], sz[threadIdx.x + off]);
            sm[threadIdx.x] = mm; sz[threadIdx.x] = ZZ;
        }
        __syncthreads();
    }
    if (threadIdx.x == 0) pairs[blockIdx.x] = make_float2(sm[0], sz[0]);
}

__global__ __launch_bounds__(256) void k6b(const float2* __restrict__ pairs, float* __restrict__ scalars, int nb) {
    __shared__ float sm[256], sz[256];
    float m = -3.402823466e38f, Z = 0.f;
    for (int j = threadIdx.x; j < nb; j += 256) {
        float2 p = pairs[j];
        smcomb(m, Z, p.x, p.y);
    }
    sm[threadIdx.x] = m; sz[threadIdx.x] = Z;
    __syncthreads();
    for (int off = 128; off > 0; off >>= 1) {
        if (threadIdx.x < off) {
            float mm = sm[threadIdx.x], ZZ = sz[threadIdx.x];
            smcomb(mm, ZZ, sm[threadIdx.x + off], sz[threadIdx.x + off]);
            sm[threadIdx.x] = mm; sz[threadIdx.x] = ZZ;
        }
        __syncthreads();
    }
    if (threadIdx.x == 0) { scalars[0] = sm[0]; scalars[1] = sz[0]; }
}

// ---------------- out[d] = sum_i softmax(g)_i * x[i,d] ----------------
__global__ __launch_bounds__(256) void k6_out(const float* __restrict__ x, const float* __restrict__ g,
        const float* __restrict__ scalars, float* __restrict__ out, int n)
{
    __shared__ float acc_s[4][DD];
    int wave = threadIdx.x >> 6, lane = threadIdx.x & 63;
    float m = scalars[0];
    float invZ = 1.0f / scalars[1];
    float a0 = 0.f, a1 = 0.f;
    int gw = blockIdx.x * 4 + wave;
    int nw = gridDim.x * 4;
    for (int i = gw; i < n; i += nw) {
        float w = expf(g[i] - m) * invZ;
        a0 += w * x[(size_t)i * DD + lane];
        a1 += w * x[(size_t)i * DD + 64 + lane];
    }
    acc_s[wave][lane] = a0;
    acc_s[wave][lane + 64] = a1;
    __syncthreads();
    if (wave == 0) {
        float v0 = acc_s[0][lane] + acc_s[1][lane] + acc_s[2][lane] + acc_s[3][lane];
        float v1 = acc_s[0][lane + 64] + acc_s[1][lane + 64] + acc_s[2][lane + 64] + acc_s[3][lane + 64];
        atomicAdd(&out[lane], v0);
        atomicAdd(&out[lane + 64], v1);
    }
}

extern "C" void kernel_launch(void* const* d_in, const int* in_sizes, int n_in,
                              void* d_out, int out_size, void* d_ws, size_t ws_size,
                              hipStream_t stream)
{
    const float* x      = (const float*)d_in[0];
    const int*   eidx   = (const int*)d_in[1];
    const float* W1rel  = (const float*)d_in[2];
    const float* b1     = (const float*)d_in[3];
    const float* W1root = (const float*)d_in[4];
    const float* W2rel  = (const float*)d_in[5];
    const float* b2     = (const float*)d_in[6];
    const float* W2root = (const float*)d_in[7];
    float* out = (float*)d_out;

    int n = in_sizes[0] / DD;
    int E = in_sizes[1] / 2;
    const int* src = eidx;
    const int* dstp = eidx + E;
    int NBK = (n + 127) >> 7;                 // buckets (<= BPAD)

    char* ws = (char*)d_ws;
    size_t off = 0;
    auto alloc = [&](size_t bytes) -> char* {
        char* p = ws + off;
        off = (off + bytes + 255) & ~(size_t)255;
        return p;
    };
    unsigned short* yb = (unsigned short*)alloc((size_t)n * LL * 2);
    unsigned short* zb = (unsigned short*)alloc((size_t)n * LL * 2);
    unsigned short* wb = (unsigned short*)alloc((size_t)DD * DD * 2);
    int*   cnt     = (int*)  alloc((size_t)n * 4);
    int*   csr_pad = (int*)  alloc((size_t)NBK * 128 * PSTRIDE * 4);
    int*   cm      = (int*)  alloc((size_t)NCHUNK * BPAD * 4);
    int*   btot    = (int*)  alloc((size_t)BPAD * 4);
    int*   bbase   = (int*)  alloc((size_t)(BPAD + 1) * 4);
    int*   sorted  = (int*)  alloc((size_t)E * 4);
    float* s       = (float*)alloc((size_t)n * 4);
    float* t       = (float*)alloc((size_t)n * 4);
    float* g       = (float*)alloc((size_t)n * 4);
    int ngate = (n + 255) / 256;
    float2* pairs  = (float2*)alloc((size_t)ngate * 8);
    float* scalars = (float*)alloc(2 * 4);
    (void)ws_size; (void)n_in;

    hipMemsetAsync(d_out, 0, (size_t)out_size * 4, stream);

    int nblk1 = (n + 63) / 64;
    kW<<<8, 256, 0, stream>>>(W1rel, W1root, wb);
    k1_scat<<<NCHUNK + nblk1, 256, 0, stream>>>(x, wb, dstp, cm, yb, zb, n, E);
    kB1<<<(BPAD + 255) / 256, 256, 0, stream>>>(cm, btot);
    kB2<<<1, 1024, 0, stream>>>(btot, bbase);
    kC<<<NCHUNK, 256, 0, stream>>>(src, dstp, cm, bbase, sorted, E);
    kD<<<NBK, 256, 0, stream>>>(sorted, bbase, cnt, csr_pad, n);
    k3_agg<<<(n + 3) / 4, 256, 0, stream>>>(yb, zb, cnt, csr_pad, b1, W2rel, W2root, s, t, n);
    k5_gate<<<ngate, 256, 0, stream>>>(s, t, cnt, csr_pad, b2, g, pairs, n);
    k6b<<<1, 256, 0, stream>>>(pairs, scalars, ngate);
    k6_out<<<512, 256, 0, stream>>>(x, g, scalars, out, n);
}

// Round 21
// 176.796 us; speedup vs baseline: 4.4843x; 1.0091x over previous
//
#include <hip/hip_runtime.h>
#include <cstdint>

#define DD 128
#define LL 64
#define NCHUNK 256          // edge chunks (radix pass A/C blocks)
#define BPAD 784            // bucket-count row stride (>= NBK=(n+127)>>7, 16-aligned)

typedef short short8 __attribute__((ext_vector_type(8)));
typedef float f32x4 __attribute__((ext_vector_type(4)));

static __device__ __forceinline__ unsigned short f2bf(float f) {
    unsigned u = __float_as_uint(f);
    unsigned r = (u + 0x7FFFu + ((u >> 16) & 1u)) >> 16;   // round-to-nearest-even
    return (unsigned short)r;
}
static __device__ __forceinline__ float bflo(unsigned u) {   // low bf16 of packed pair
    return __uint_as_float(u << 16);
}
static __device__ __forceinline__ float bfhi(unsigned u) {   // high bf16 of packed pair
    return __uint_as_float(u & 0xFFFF0000u);
}
static __device__ __forceinline__ uint4 pack8(float4 lo, float4 hi) {
    uint4 u;
    u.x = (unsigned)f2bf(lo.x) | ((unsigned)f2bf(lo.y) << 16);
    u.y = (unsigned)f2bf(lo.z) | ((unsigned)f2bf(lo.w) << 16);
    u.z = (unsigned)f2bf(hi.x) | ((unsigned)f2bf(hi.y) << 16);
    u.w = (unsigned)f2bf(hi.z) | ((unsigned)f2bf(hi.w) << 16);
    return u;
}

// ---------------- prologue: W1_rel||W1_root -> combined bf16 wb[128][128] ----------------
// (Round-19 lesson stands: f32 LDS atomicAdd = CAS loop; only INT LDS atomics.)
__global__ __launch_bounds__(256) void kW(const float* __restrict__ Wrel, const float* __restrict__ Wroot,
        unsigned short* __restrict__ wb)
{
    int c = blockIdx.x * 256 + threadIdx.x;   // 2048 chunks of 8 elements
    if (c >= 2048) return;
    int r = c >> 4, cb = (c & 15) * 8;
    const float* srcp = (r < 64) ? (Wrel + (size_t)r * DD + cb) : (Wroot + (size_t)(r - 64) * DD + cb);
    float4 lo = *(const float4*)srcp;
    float4 hi = *(const float4*)(srcp + 4);
    *(uint4*)(wb + (size_t)r * DD + cb) = pack8(lo, hi);
}

// ---------------- fused: radix pass A (chunk histograms, blocks [0,NCHUNK)) + MFMA GEMM ----------------
__global__ __launch_bounds__(256) void k1_scat(const float* __restrict__ x,
        const unsigned short* __restrict__ wb,
        const int* __restrict__ dst, int* __restrict__ cm,
        unsigned short* __restrict__ yb, unsigned short* __restrict__ zb,
        int n, int E)
{
    __shared__ __align__(16) unsigned short xa[64 * 128];    // 16KB; hist alias / GEMM stage / epilogue
    int tid = threadIdx.x;
    if (blockIdx.x < NCHUNK) {                  // ---- pass A: chunk histogram ----
        int* hist = (int*)xa;
        int c = blockIdx.x;
        for (int i = tid; i < BPAD; i += 256) hist[i] = 0;
        __syncthreads();
        int CH = (E + NCHUNK - 1) / NCHUNK;
        int base = c * CH, end = base + CH; if (end > E) end = E;
        for (int e = base + tid; e < end; e += 256)
            atomicAdd(&hist[dst[e] >> 7], 1);                 // LDS atomic (int: native)
        __syncthreads();
        for (int i = tid; i < BPAD; i += 256) cm[c * BPAD + i] = hist[i];
        return;
    }
    // ---- GEMM part: [yb|zb] = bf16(x @ [W1_rel|W1_root]^T) ----
    int nbase = (blockIdx.x - NCHUNK) * 64;

    { // stage x: 4 lanes per row (coalesced: each wave reads 16 rows contiguous)
        int r = tid >> 2, cb = (tid & 3) * 4;
        int node = nbase + r; if (node >= n) node = n - 1;
        const float4* xp = (const float4*)(x + (size_t)node * DD);
        #pragma unroll
        for (int c = 0; c < 4; ++c) {
            float4 lo = xp[(cb + c) * 2], hi = xp[(cb + c) * 2 + 1];
            int slot = (cb + c + r) & 15;
            *(uint4*)&xa[r * 128 + slot * 8] = pack8(lo, hi);
        }
    }
    __syncthreads();

    int lane = tid & 63;
    int w = __builtin_amdgcn_readfirstlane(tid >> 6);
    int lr = lane & 15, lk = lane >> 4;
    int wrowbase = w * 32;                    // combined wb row block (w*32 + tc*16 + lr)

    f32x4 acc[4][2];
    #pragma unroll
    for (int tr = 0; tr < 4; ++tr)
        #pragma unroll
        for (int tc = 0; tc < 2; ++tc)
            acc[tr][tc] = (f32x4){0.f, 0.f, 0.f, 0.f};

    #pragma unroll
    for (int kk = 0; kk < 4; ++kk) {
        int c = kk * 4 + lk;
        short8 bfrag[2];
        #pragma unroll
        for (int tc = 0; tc < 2; ++tc)        // single 16B load from L2-hot preconverted wb
            bfrag[tc] = *(const short8*)(wb + (size_t)(wrowbase + tc * 16 + lr) * DD + kk * 32 + lk * 8);
        #pragma unroll
        for (int tr = 0; tr < 4; ++tr) {
            int arow = tr * 16 + lr;
            short8 afrag = *(const short8*)&xa[arow * 128 + ((c + arow) & 15) * 8];
            acc[tr][0] = __builtin_amdgcn_mfma_f32_16x16x32_bf16(afrag, bfrag[0], acc[tr][0], 0, 0, 0);
            acc[tr][1] = __builtin_amdgcn_mfma_f32_16x16x32_bf16(afrag, bfrag[1], acc[tr][1], 0, 0, 0);
        }
    }

    __syncthreads();                 // xa reads done; reuse as epilogue buffer
    unsigned short* ob = xa;         // [64 rows][128 cols] bf16, 32B-group XOR swizzle
    #pragma unroll
    for (int tr = 0; tr < 4; ++tr) {
        #pragma unroll
        for (int tc = 0; tc < 2; ++tc) {
            int col = w * 32 + tc * 16 + lr;      // C/D: col=lane&15 [m89]
            int cg = col >> 4, ci = col & 15;
            #pragma unroll
            for (int r = 0; r < 4; ++r) {
                int row = tr * 16 + lk * 4 + r;   // C/D: row=(lane>>4)*4+reg [m89]
                ob[row * 128 + ((cg ^ (row & 7)) << 4) + ci] = f2bf(acc[tr][tc][r]);
            }
        }
    }
    __syncthreads();

    { // coalesced store: yb = cols 0-63, zb = cols 64-127
        int row = tid >> 2, part = tid & 3;
        int node = nbase + row;
        if (node < n) {
            int by = row * 128 + ((part ^ (row & 7)) << 4);
            uint4 a0 = *(uint4*)&ob[by];
            uint4 a1 = *(uint4*)&ob[by + 8];
            *(uint4*)(yb + (size_t)node * LL + part * 16) = a0;
            *(uint4*)(yb + (size_t)node * LL + part * 16 + 8) = a1;
            int bz = row * 128 + (((part + 4) ^ (row & 7)) << 4);
            uint4 b0 = *(uint4*)&ob[bz];
            uint4 b1 = *(uint4*)&ob[bz + 8];
            *(uint4*)(zb + (size_t)node * LL + part * 16) = b0;
            *(uint4*)(zb + (size_t)node * LL + part * 16 + 8) = b1;
        }
    }
}

// ---------------- radix pass B1: per-bucket column rewrite (parallel) ----------------
__global__ __launch_bounds__(256) void kB1(int* __restrict__ cm, int* __restrict__ btot) {
    int b = blockIdx.x * 256 + threadIdx.x;
    if (b >= BPAD) return;
    int run = 0;
    for (int c = 0; c < NCHUNK; ++c) {
        int v = cm[c * BPAD + b];
        cm[c * BPAD + b] = run;
        run += v;
    }
    btot[b] = run;
}

// ---------------- radix pass B2: scan bucket totals -> bbase ----------------
__global__ __launch_bounds__(1024) void kB2(const int* __restrict__ btot, int* __restrict__ bbase) {
    __shared__ int sc[1024];
    int b = threadIdx.x;
    int v = (b < BPAD) ? btot[b] : 0;
    sc[b] = v;
    __syncthreads();
    for (int off = 1; off < 1024; off <<= 1) {
        int add = (b >= off) ? sc[b - off] : 0;
        __syncthreads();
        sc[b] += add;
        __syncthreads();
    }
    if (b < BPAD) bbase[b] = sc[b] - v;
    if (b == 1023) bbase[BPAD] = sc[b];      // = E
}

// ---------------- radix pass C: place edges into bucket-sorted order ----------------
__global__ __launch_bounds__(256) void kC(const int* __restrict__ src, const int* __restrict__ dst,
        const int* __restrict__ cm, const int* __restrict__ bbase, int* __restrict__ sorted, int E)
{
    __shared__ int run[BPAD];
    int c = blockIdx.x;
    for (int i = threadIdx.x; i < BPAD; i += 256) run[i] = cm[c * BPAD + i] + bbase[i];
    __syncthreads();
    int CH = (E + NCHUNK - 1) / NCHUNK;
    int base = c * CH, end = base + CH; if (end > E) end = E;
    for (int e = base + threadIdx.x; e < end; e += 256) {
        int d = dst[e];
        int pos = atomicAdd(&run[d >> 7], 1);             // LDS atomic; positions exact
        sorted[pos] = ((d & 127) << 17) | src[e];         // src < 2^17 (n <= 131071)
    }
}

// ---------------- radix pass D: bucket -> COMPACT node-sorted elist + rowptr ----------------
// Round-20 trim: padded csr_pad scattered 16/64 slots per 256B row -> ~4x
// partial-line writeback amp. Two-pass counting sort emits a dense elist
// (each bucket writes ONE contiguous ~8KB span from one block -> clean
// single-XCD writeback) + rowptr (globally contiguous: start(i+1)=end(i)).
__global__ __launch_bounds__(256) void kD(const int* __restrict__ sorted, const int* __restrict__ bbase,
        int* __restrict__ rowptr, int* __restrict__ elist, int n, int E)
{
    __shared__ int hist[128];
    __shared__ int incl[128];
    __shared__ int cur[128];
    int tid = threadIdx.x;
    int b = blockIdx.x;
    int lo = bbase[b], hi = bbase[b + 1];
    if (tid < 128) hist[tid] = 0;
    __syncthreads();
    for (int e = lo + tid; e < hi; e += 256)
        atomicAdd(&hist[sorted[e] >> 17], 1);             // LDS int atomic (native)
    __syncthreads();
    if (tid < 128) incl[tid] = hist[tid];
    __syncthreads();
    for (int off = 1; off < 128; off <<= 1) {             // Hillis-Steele inclusive scan
        int add = (tid < 128 && tid >= off) ? incl[tid - off] : 0;
        __syncthreads();
        if (tid < 128) incl[tid] += add;
        __syncthreads();
    }
    if (tid < 128) {
        int start = lo + incl[tid] - hist[tid];           // exclusive prefix
        cur[tid] = start;
        int node = b * 128 + tid;
        if (node <= n) rowptr[node] = start;              // node==n -> rowptr[n]=E
    }
    __syncthreads();
    for (int e = lo + tid; e < hi; e += 256) {
        int v = sorted[e];
        int pos = atomicAdd(&cur[v >> 17], 1);            // LDS int atomic = placement
        elist[pos] = v & 0x1FFFF;
    }
}

// ---------------- layer-1 aggregate + h + s,t (one wave per node, quarter-lane) ----------------
__global__ __launch_bounds__(256) void k3_agg(const unsigned short* __restrict__ yb, const unsigned short* __restrict__ zb,
        const int* __restrict__ rowptr, const int* __restrict__ elist,
        const float* __restrict__ b1, const float* __restrict__ w2rel, const float* __restrict__ w2root,
        float* __restrict__ s, float* __restrict__ t, int n)
{
    int wave = threadIdx.x >> 6, lane = threadIdx.x & 63;
    int i = blockIdx.x * 4 + wave;
    if (i >= n) return;
    int st = rowptr[i], en = rowptr[i + 1];
    int deg = en - st;
    const int* cp = elist + st;                      // wave-uniform base -> s_load
    int c4 = lane & 15, q = lane >> 4;               // feature chunk (4 bf16), quarter
    float a0 = 0.f, a1 = 0.f, a2 = 0.f, a3 = 0.f;
    for (int k = 0; k < deg; k += 16) {
        int e0 = k + q, e1 = k + 4 + q, e2 = k + 8 + q, e3 = k + 12 + q;
        uint2 u0 = make_uint2(0u, 0u), u1 = u0, u2 = u0, u3 = u0;
        if (e0 < deg) u0 = *(const uint2*)(yb + (size_t)cp[e0] * LL + c4 * 4);
        if (e1 < deg) u1 = *(const uint2*)(yb + (size_t)cp[e1] * LL + c4 * 4);
        if (e2 < deg) u2 = *(const uint2*)(yb + (size_t)cp[e2] * LL + c4 * 4);
        if (e3 < deg) u3 = *(const uint2*)(yb + (size_t)cp[e3] * LL + c4 * 4);
        a0 += (bflo(u0.x) + bflo(u1.x)) + (bflo(u2.x) + bflo(u3.x));
        a1 += (bfhi(u0.x) + bfhi(u1.x)) + (bfhi(u2.x) + bfhi(u3.x));
        a2 += (bflo(u0.y) + bflo(u1.y)) + (bflo(u2.y) + bflo(u3.y));
        a3 += (bfhi(u0.y) + bfhi(u1.y)) + (bfhi(u2.y) + bfhi(u3.y));
    }
    // collapse quarters (lanes with same c4 hold partial sums)
    a0 += __shfl_xor(a0, 16, 64); a0 += __shfl_xor(a0, 32, 64);
    a1 += __shfl_xor(a1, 16, 64); a1 += __shfl_xor(a1, 32, 64);
    a2 += __shfl_xor(a2, 16, 64); a2 += __shfl_xor(a2, 32, 64);
    a3 += __shfl_xor(a3, 16, 64); a3 += __shfl_xor(a3, 32, 64);

    uint2 uz = *(const uint2*)(zb + (size_t)i * LL + c4 * 4);
    float4 bv = *(const float4*)(b1 + c4 * 4);
    float h0 = a0 + bflo(uz.x) + bv.x;
    float h1 = a1 + bfhi(uz.x) + bv.y;
    float h2 = a2 + bflo(uz.y) + bv.z;
    float h3 = a3 + bfhi(uz.y) + bv.w;
    h0 = h0 > 0.f ? h0 : 0.2f * h0;          // leaky_relu(0.2)
    h1 = h1 > 0.f ? h1 : 0.2f * h1;
    h2 = h2 > 0.f ? h2 : 0.2f * h2;
    h3 = h3 > 0.f ? h3 : 0.2f * h3;
    float4 wr = *(const float4*)(w2rel + c4 * 4);
    float4 wo = *(const float4*)(w2root + c4 * 4);
    float sv = h0 * wr.x + h1 * wr.y + h2 * wr.z + h3 * wr.w;
    float tv = h0 * wo.x + h1 * wo.y + h2 * wo.z + h3 * wo.w;
    #pragma unroll
    for (int o = 8; o >= 1; o >>= 1) {       // reduce across the 16 c4 groups
        sv += __shfl_xor(sv, o, 64);
        tv += __shfl_xor(tv, o, 64);
    }
    if (lane == 0) { s[i] = sv; t[i] = tv; }
}

// ---------------- gate logits + per-block online-softmax (m,Z) ----------------
static __device__ __forceinline__ void smcomb(float& m, float& Z, float m2, float Z2) {
    float M = fmaxf(m, m2);
    Z = Z * expf(m - M) + Z2 * expf(m2 - M);
    m = M;
}

__global__ __launch_bounds__(256) void k5_gate(const float* __restrict__ s, const float* __restrict__ t,
        const int* __restrict__ rowptr, const int* __restrict__ elist, const float* __restrict__ b2,
        float* __restrict__ g, float2* __restrict__ pairs, int n)
{
    __shared__ float sm[256], sz[256];
    int i = blockIdx.x * 256 + threadIdx.x;
    float m = -3.402823466e38f, Z = 0.f;
    if (i < n) {
        float acc = b2[0] + t[i];
        int st = rowptr[i], en = rowptr[i + 1];
        int deg = en - st;
        const int* cp = elist + st;
        int e = 0;
        for (; e + 4 <= deg; e += 4)
            acc += (s[cp[e]] + s[cp[e + 1]]) + (s[cp[e + 2]] + s[cp[e + 3]]);
        for (; e < deg; ++e) acc += s[cp[e]];
        g[i] = acc;
        m = acc; Z = 1.f;
    }
    sm[threadIdx.x] = m; sz[threadIdx.x] = Z;
    __syncthreads();
    for (int off = 128; off > 0; off >>= 1) {
        if (threadIdx.x < off) {
            float mm = sm[threadIdx.x], ZZ = sz[threadIdx.x];
            smcomb(mm, ZZ, sm[threadIdx.x + off], sz[threadIdx.x + off]);
            sm[threadIdx.x] = mm; sz[threadIdx.x] = ZZ;
        }
        __syncthreads();
    }
    if (threadIdx.x == 0) pairs[blockIdx.x] = make_float2(sm[0], sz[0]);
}

// ---------------- out[d] = sum_i softmax(g)_i * x[i,d]  (pair-reduce folded in) ----------------
__global__ __launch_bounds__(256) void k6_out(const float* __restrict__ x, const float* __restrict__ g,
        const float2* __restrict__ pairs, int npairs, float* __restrict__ out, int n)
{
    __shared__ float acc_s[4][DD];
    __shared__ float sm[256], sz[256];
    int tid = threadIdx.x;
    // redundant per-block reduction of the (m,Z) pairs (3KB, L2-broadcast)
    float m = -3.402823466e38f, Z = 0.f;
    for (int j = tid; j < npairs; j += 256) {
        float2 p = pairs[j];
        smcomb(m, Z, p.x, p.y);
    }
    sm[tid] = m; sz[tid] = Z;
    __syncthreads();
    for (int off = 128; off > 0; off >>= 1) {
        if (tid < off) {
            float mm = sm[tid], ZZ = sz[tid];
            smcomb(mm, ZZ, sm[tid + off], sz[tid + off]);
            sm[tid] = mm; sz[tid] = ZZ;
        }
        __syncthreads();
    }
    float M = sm[0];
    float invZ = 1.0f / sz[0];

    int wave = tid >> 6, lane = tid & 63;
    float a0 = 0.f, a1 = 0.f;
    int gw = blockIdx.x * 4 + wave;
    int nw = gridDim.x * 4;
    for (int i = gw; i < n; i += nw) {
        float w = expf(g[i] - M) * invZ;
        a0 += w * x[(size_t)i * DD + lane];
        a1 += w * x[(size_t)i * DD + 64 + lane];
    }
    acc_s[wave][lane] = a0;
    acc_s[wave][lane + 64] = a1;
    __syncthreads();
    if (wave == 0) {
        float v0 = acc_s[0][lane] + acc_s[1][lane] + acc_s[2][lane] + acc_s[3][lane];
        float v1 = acc_s[0][lane + 64] + acc_s[1][lane + 64] + acc_s[2][lane + 64] + acc_s[3][lane + 64];
        atomicAdd(&out[lane], v0);
        atomicAdd(&out[lane + 64], v1);
    }
}

extern "C" void kernel_launch(void* const* d_in, const int* in_sizes, int n_in,
                              void* d_out, int out_size, void* d_ws, size_t ws_size,
                              hipStream_t stream)
{
    const float* x      = (const float*)d_in[0];
    const int*   eidx   = (const int*)d_in[1];
    const float* W1rel  = (const float*)d_in[2];
    const float* b1     = (const float*)d_in[3];
    const float* W1root = (const float*)d_in[4];
    const float* W2rel  = (const float*)d_in[5];
    const float* b2     = (const float*)d_in[6];
    const float* W2root = (const float*)d_in[7];
    float* out = (float*)d_out;

    int n = in_sizes[0] / DD;
    int E = in_sizes[1] / 2;
    const int* src = eidx;
    const int* dstp = eidx + E;
    int NBK = (n + 127) >> 7;                 // buckets (<= BPAD)

    char* ws = (char*)d_ws;
    size_t off = 0;
    auto alloc = [&](size_t bytes) -> char* {
        char* p = ws + off;
        off = (off + bytes + 255) & ~(size_t)255;
        return p;
    };
    unsigned short* yb = (unsigned short*)alloc((size_t)n * LL * 2);
    unsigned short* zb = (unsigned short*)alloc((size_t)n * LL * 2);
    unsigned short* wb = (unsigned short*)alloc((size_t)DD * DD * 2);
    int*   rowptr  = (int*)  alloc((size_t)(n + 1) * 4);
    int*   elist   = (int*)  alloc((size_t)E * 4);
    int*   cm      = (int*)  alloc((size_t)NCHUNK * BPAD * 4);
    int*   btot    = (int*)  alloc((size_t)BPAD * 4);
    int*   bbase   = (int*)  alloc((size_t)(BPAD + 1) * 4);
    int*   sorted  = (int*)  alloc((size_t)E * 4);
    float* s       = (float*)alloc((size_t)n * 4);
    float* t       = (float*)alloc((size_t)n * 4);
    float* g       = (float*)alloc((size_t)n * 4);
    int ngate = (n + 255) / 256;
    float2* pairs  = (float2*)alloc((size_t)ngate * 8);
    (void)ws_size; (void)n_in;

    hipMemsetAsync(d_out, 0, (size_t)out_size * 4, stream);

    int nblk1 = (n + 63) / 64;
    kW<<<8, 256, 0, stream>>>(W1rel, W1root, wb);
    k1_scat<<<NCHUNK + nblk1, 256, 0, stream>>>(x, wb, dstp, cm, yb, zb, n, E);
    kB1<<<(BPAD + 255) / 256, 256, 0, stream>>>(cm, btot);
    kB2<<<1, 1024, 0, stream>>>(btot, bbase);
    kC<<<NCHUNK, 256, 0, stream>>>(src, dstp, cm, bbase, sorted, E);
    kD<<<NBK, 256, 0, stream>>>(sorted, bbase, rowptr, elist, n, E);
    k3_agg<<<(n + 3) / 4, 256, 0, stream>>>(yb, zb, rowptr, elist, b1, W2rel, W2root, s, t, n);
    k5_gate<<<ngate, 256, 0, stream>>>(s, t, rowptr, elist, b2, g, pairs, n);
    k6_out<<<512, 256, 0, stream>>>(x, g, pairs, ngate, out, n);
}